// Round 4
// baseline (45.672 us; speedup 1.0000x reference)
//
#include <hip/hip_runtime.h>
#include <stdint.h>

// MosaicSDF: N=1024 points, G=512 grids, K=7 (343 nodes/grid).
// R4: pair-list decomposition.
//   build : block per grid -> LDS-compact active (g,n) pairs (packed u32)
//           into a global grid-clustered list; den[n] += gwr atomics.
//   pairs : one LANE per pair. Separable distance: dy2[7], dz2[7] in
//           registers (static idx via unroll), ~6 VALU/node, gv[] loads
//           near-uniform across the wave (same grid) -> broadcast.
//   final : out[n] = den>0 ? num/den : 0.

#define NPTS   1024
#define NGRIDS 512
#define KCUBE  343
#define STEP   (1.0f / 6.0f)

// workspace layout (floats): num[1024] | den[1024] | cnt | pad | list[524288]
#define WS_NUM   0
#define WS_DEN   1024
#define WS_CNT   2048
#define WS_LIST  2304          // 16B-aligned
#define PAIRS_WAVES 2048       // 512 blocks x 256 thr

__global__ __launch_bounds__(256) void msdf_build(
    const float* __restrict__ points,    // (N,3)
    const float* __restrict__ centers,   // (G,3)
    const float* __restrict__ scales,    // (G,)
    float* __restrict__ den,             // (N,)   pre-zeroed
    uint32_t* __restrict__ list,         // (<=N*G,)
    int* __restrict__ cnt)               // pre-zeroed
{
    __shared__ int s_n[NPTS];
    __shared__ int s_cnt;
    __shared__ int s_base;

    const int g = blockIdx.x;
    const int t = threadIdx.x;
    if (t == 0) s_cnt = 0;

    const float cx   = centers[g * 3 + 0];
    const float cy   = centers[g * 3 + 1];
    const float cz   = centers[g * 3 + 2];
    const float invs = 1.0f / scales[g];
    __syncthreads();

    #pragma unroll
    for (int k = 0; k < NPTS / 256; ++k) {
        const int n = k * 256 + t;
        const float rx = (points[n * 3 + 0] - cx) * invs;
        const float ry = (points[n * 3 + 1] - cy) * invs;
        const float rz = (points[n * 3 + 2] - cz) * invs;
        const float gwr = 1.0f - sqrtf(rx * rx + ry * ry + rz * rz);
        if (gwr > 0.0f) {
            const int slot = atomicAdd(&s_cnt, 1);
            s_n[slot] = n;
            atomicAdd(&den[n], gwr);
        }
    }
    __syncthreads();
    if (t == 0) s_base = atomicAdd(cnt, s_cnt);
    __syncthreads();

    const int base = s_base, c = s_cnt;
    for (int i = t; i < c; i += 256)
        list[base + i] = ((uint32_t)g << 10) | (uint32_t)s_n[i];
}

__global__ __launch_bounds__(256) void msdf_pairs(
    const float* __restrict__ points,
    const float* __restrict__ centers,
    const float* __restrict__ scales,
    const float* __restrict__ vals,      // (G,343)
    const uint32_t* __restrict__ list,
    const int* __restrict__ cnt,
    float* __restrict__ num)             // (N,)   pre-zeroed
{
    const int lane = threadIdx.x & 63;
    const int wid  = blockIdx.x * (256 / 64) + (threadIdx.x >> 6);
    const int total   = *cnt;
    const int nchunks = (total + 63) >> 6;

    for (int chunk = wid; chunk < nchunks; chunk += PAIRS_WAVES) {
        const int idx = chunk * 64 + lane;
        if (idx >= total) continue;

        const uint32_t e = list[idx];
        const int g = (int)(e >> 10);
        const int n = (int)(e & 1023u);

        const float invs = 1.0f / scales[g];
        const float rx = (points[n * 3 + 0] - centers[g * 3 + 0]) * invs;
        const float ry = (points[n * 3 + 1] - centers[g * 3 + 1]) * invs;
        const float rz = (points[n * 3 + 2] - centers[g * 3 + 2]) * invs;
        const float gwr = 1.0f - sqrtf(rx * rx + ry * ry + rz * rz);

        // Separable per-axis squared distances, register-resident.
        float dy2[7], dz2[7];
        #pragma unroll
        for (int j = 0; j < 7; ++j) { const float d = ry - j * STEP; dy2[j] = d * d; }
        #pragma unroll
        for (int l = 0; l < 7; ++l) { const float d = rz - l * STEP; dz2[l] = d * d; }

        const float* __restrict__ gv = vals + g * KCUBE;
        float wsum = 0.0f, vsum = 0.0f;
        float tx = rx;
        #pragma unroll 1                          // keep i rolled (I-cache)
        for (int i = 0; i < 7; ++i) {
            const float dx2 = tx * tx;
            tx -= STEP;
            const int cbase = i * 49;
            #pragma unroll
            for (int j = 0; j < 7; ++j) {
                const float dxy = dx2 + dy2[j];
                #pragma unroll
                for (int l = 0; l < 7; ++l) {
                    const float d2 = dxy + dz2[l];
                    const float wt = (d2 <= 1.0f) ? sqrtf(d2) : 0.0f;
                    wsum += wt;
                    vsum  = fmaf(wt, gv[cbase + j * 7 + l], vsum);
                }
            }
        }
        const float interp = (wsum > 0.0f) ? (vsum / wsum) : 0.0f;
        atomicAdd(&num[n], interp * gwr);
    }
}

__global__ __launch_bounds__(256) void msdf_final(
    const float* __restrict__ num,
    const float* __restrict__ den,
    float* __restrict__ out)
{
    const int n = blockIdx.x * blockDim.x + threadIdx.x;
    if (n < NPTS) {
        const float d = den[n];
        out[n] = (d > 0.0f) ? (num[n] / d) : 0.0f;
    }
}

extern "C" void kernel_launch(void* const* d_in, const int* in_sizes, int n_in,
                              void* d_out, int out_size, void* d_ws, size_t ws_size,
                              hipStream_t stream) {
    const float* points  = (const float*)d_in[0];   // (1024,3)
    const float* centers = (const float*)d_in[1];   // (512,3)
    const float* scales  = (const float*)d_in[2];   // (512,)
    const float* vals    = (const float*)d_in[3];   // (512,7,7,7)
    float* out = (float*)d_out;                     // (1024,)

    float*    num  = (float*)d_ws + WS_NUM;
    float*    den  = (float*)d_ws + WS_DEN;
    int*      cnt  = (int*)((float*)d_ws + WS_CNT);
    uint32_t* list = (uint32_t*)((float*)d_ws + WS_LIST);

    // zero num, den, cnt (covers up to WS_LIST)
    hipMemsetAsync(d_ws, 0, WS_LIST * sizeof(float), stream);
    msdf_build<<<NGRIDS, 256, 0, stream>>>(points, centers, scales, den, list, cnt);
    msdf_pairs<<<512, 256, 0, stream>>>(points, centers, scales, vals, list, cnt, num);
    msdf_final<<<(NPTS + 255) / 256, 256, 0, stream>>>(num, den, out);
}

// Round 5
// 18.877 us; speedup vs baseline: 2.4195x; 2.4195x over previous
//
#include <hip/hip_runtime.h>

// MosaicSDF: N=1024 points, G=512 grids, K=7 (343 nodes/grid).
// R5: single fused kernel, one block (128 thr = 2 waves) per point.
//   Phase 1: waves sweep 512 grids (4 ballot rounds each), compute
//            gwr = relu(1-||rel||), compact active grid ids into LDS via
//            ballot-prefix scan (deterministic, no atomics), reduce den.
//   Phase 2: one lane per active pair; separable distance tables in
//            registers (static unroll), ~6 VALU + 1 L1-resident load per
//            node; butterfly reduce; write out[n]. No workspace/memset.

#define NPTS   1024
#define NGRIDS 512
#define KCUBE  343
#define STEP   (1.0f / 6.0f)
#define FSQRT(x) __builtin_amdgcn_sqrtf(x)

__global__ __launch_bounds__(128) void msdf_fused(
    const float* __restrict__ points,    // (N,3)
    const float* __restrict__ centers,   // (G,3)
    const float* __restrict__ scales,    // (G,)
    const float* __restrict__ vals,      // (G,343)
    float* __restrict__ out)             // (N,)
{
    __shared__ unsigned short s_g[2][256];   // per-half compacted grid ids
    __shared__ int   s_c[2];
    __shared__ float s_d[2];
    __shared__ float s_a[2];

    const int n    = blockIdx.x;
    const int t    = threadIdx.x;
    const int h    = t >> 6;             // wave half: grids [h*256, h*256+256)
    const int lane = t & 63;

    const float px = points[n * 3 + 0];  // uniform -> scalar loads
    const float py = points[n * 3 + 1];
    const float pz = points[n * 3 + 2];

    // ---- Phase 1: activity sweep + ballot-scan compaction ----
    float dsum  = 0.0f;
    int   cbase = 0;
    #pragma unroll
    for (int r = 0; r < 4; ++r) {
        const int g = h * 256 + r * 64 + lane;
        const float invs = 1.0f / scales[g];
        const float rx = (px - centers[g * 3 + 0]) * invs;
        const float ry = (py - centers[g * 3 + 1]) * invs;
        const float rz = (pz - centers[g * 3 + 2]) * invs;
        const float gwr = 1.0f - FSQRT(rx * rx + ry * ry + rz * rz);
        const bool  act = (gwr > 0.0f);
        const unsigned long long m = __ballot(act);
        if (act) {
            const int pos = cbase + (int)__popcll(m & ((1ull << lane) - 1ull));
            s_g[h][pos] = (unsigned short)g;
            dsum += gwr;
        }
        cbase += (int)__popcll(m);
    }
    #pragma unroll
    for (int off = 32; off >= 1; off >>= 1) dsum += __shfl_xor(dsum, off);
    if (lane == 0) { s_c[h] = cbase; s_d[h] = dsum; }
    __syncthreads();

    // ---- Phase 2: one lane per active pair ----
    const int   c0  = s_c[0];
    const int   C   = c0 + s_c[1];
    const float den = s_d[0] + s_d[1];

    float acc = 0.0f;
    for (int a = h * 64 + lane; a < C; a += 128) {
        const int g = (a < c0) ? (int)s_g[0][a] : (int)s_g[1][a - c0];

        const float invs = 1.0f / scales[g];
        const float rx = (px - centers[g * 3 + 0]) * invs;
        const float ry = (py - centers[g * 3 + 1]) * invs;
        const float rz = (pz - centers[g * 3 + 2]) * invs;
        const float gwr = 1.0f - FSQRT(rx * rx + ry * ry + rz * rz);

        // Separable per-axis squared distances (static indices -> regs).
        float dy2[7], dz2[7];
        #pragma unroll
        for (int j = 0; j < 7; ++j) { const float d = ry - j * STEP; dy2[j] = d * d; }
        #pragma unroll
        for (int l = 0; l < 7; ++l) { const float d = rz - l * STEP; dz2[l] = d * d; }

        const float* __restrict__ gv = vals + g * KCUBE;
        float wsum = 0.0f, vsum = 0.0f;
        float tx = rx;                       // running dx (no runtime-idx array)
        #pragma unroll 1
        for (int i = 0; i < 7; ++i) {
            const float dx2 = tx * tx;
            tx -= STEP;
            const float* __restrict__ gvi = gv + i * 49;
            #pragma unroll
            for (int j = 0; j < 7; ++j) {
                const float dxy = dx2 + dy2[j];
                #pragma unroll
                for (int l = 0; l < 7; ++l) {
                    const float d2 = dxy + dz2[l];
                    const float wt = (d2 <= 1.0f) ? FSQRT(d2) : 0.0f;
                    wsum += wt;
                    vsum  = fmaf(wt, gvi[j * 7 + l], vsum);
                }
            }
        }
        const float interp = (wsum > 0.0f) ? (vsum / wsum) : 0.0f;
        acc += interp * gwr;
    }

    #pragma unroll
    for (int off = 32; off >= 1; off >>= 1) acc += __shfl_xor(acc, off);
    if (lane == 0) s_a[h] = acc;
    __syncthreads();
    if (t == 0)
        out[n] = (den > 0.0f) ? ((s_a[0] + s_a[1]) / den) : 0.0f;
}

extern "C" void kernel_launch(void* const* d_in, const int* in_sizes, int n_in,
                              void* d_out, int out_size, void* d_ws, size_t ws_size,
                              hipStream_t stream) {
    const float* points  = (const float*)d_in[0];   // (1024,3)
    const float* centers = (const float*)d_in[1];   // (512,3)
    const float* scales  = (const float*)d_in[2];   // (512,)
    const float* vals    = (const float*)d_in[3];   // (512,7,7,7)
    float* out = (float*)d_out;                     // (1024,)

    msdf_fused<<<NPTS, 128, 0, stream>>>(points, centers, scales, vals, out);
}